// Round 14
// baseline (429.445 us; speedup 1.0000x reference)
//
#include <hip/hip_runtime.h>

#define B_   8192
#define K_   5
#define D_   128
#define QD_  129
#define KD_  1285
#define SQ_  132      // padded fp32 row stride (oacc, attn0 LDS)
#define BK_  40960    // B_*K_
#define QPAD 160      // bf16 k-dim padding (5 x 32)
#define KDP  1312     // KD_ padded to 41*32

typedef unsigned short u16;
typedef unsigned int   u32;
typedef __attribute__((ext_vector_type(8))) short bf8_t;
typedef __attribute__((ext_vector_type(4))) float f4_t;
typedef __attribute__((ext_vector_type(16))) float f16f;
typedef __attribute__((address_space(3))) u32 lds_u32;
typedef __attribute__((address_space(1))) const u32 glob_u32;

#define MFMA16(a, b, c) __builtin_amdgcn_mfma_f32_16x16x32_bf16(a, b, c, 0, 0, 0)
#define MFMA32(a, b, c) __builtin_amdgcn_mfma_f32_32x32x16_bf16(a, b, c, 0, 0, 0)

__device__ __forceinline__ u16 f2bf(float x) {
  u32 u = __float_as_uint(x);
  u = (u + 0x7fffu + ((u >> 16) & 1u)) >> 16;
  return (u16)u;
}
__device__ __forceinline__ float bf2f(u16 v) {
  return __uint_as_float((u32)v << 16);
}
__device__ __forceinline__ u32 pack2(float a, float b) {
  return (u32)f2bf(a) | ((u32)f2bf(b) << 16);
}
__device__ __forceinline__ float exp2_fast(float x) {
  float r; asm("v_exp_f32 %0, %1" : "=v"(r) : "v"(x)); return r;
}
__device__ __forceinline__ u32 cvtpk(float a, float b) {
  u32 r;
  asm("v_cvt_pk_bf16_f32 %0, %1, %2" : "=v"(r) : "v"(a), "v"(b));
  return r;
}
__device__ __forceinline__ int swz8(int row, int seg) {
  return (row << 5) + (((seg ^ (row >> 1)) & 3) << 3);
}
__device__ __forceinline__ void gload16(const u16* src, u16* ldsdst) {
  __builtin_amdgcn_global_load_lds((glob_u32*)src, (lds_u32*)ldsdst, 16, 0, 0);
}
#define WAIT_VM0() asm volatile("s_waitcnt vmcnt(0)" ::: "memory")
#define WAIT_VM4() asm volatile("s_waitcnt vmcnt(4)" ::: "memory")
#define WAIT_VM5() asm volatile("s_waitcnt vmcnt(5)" ::: "memory")
#define WAIT_VM10() asm volatile("s_waitcnt vmcnt(10)" ::: "memory")
#define WAIT_LGKM0() asm volatile("s_waitcnt lgkmcnt(0)" ::: "memory")

// ---------------------------------------------------------------------------
// One-time weight conversion fp32 -> bf16 with zero padding.
//   wkv [288][1312] @0        rows 0-128 Wk, 129-257 Wv
//   wq  [144][160]  @377856
//   wo  [144][160]  @400896
//   w1  [144][320]  @423936   (cols: 0-128 = W1[:,0:129], 160-287 = W1[:,129:257])
//   w2  [144][128]  @470016   (end 488448)
// ---------------------------------------------------------------------------
__global__ __launch_bounds__(256) void convw_k(
    const float* __restrict__ Wq, const float* __restrict__ Wk,
    const float* __restrict__ Wv, const float* __restrict__ Wo,
    const float* __restrict__ W1, const float* __restrict__ W2,
    u16* __restrict__ wb)
{
  int idx = blockIdx.x * 256 + threadIdx.x;
  if (idx < 377856) {
    int r = idx / KDP, c = idx - r * KDP;
    float v = 0.f;
    if (c < KD_) {
      if (r < 129) v = Wk[r * KD_ + c];
      else if (r < 258) v = Wv[(r - 129) * KD_ + c];
    }
    wb[idx] = f2bf(v);
    return;
  }
  int i2 = idx - 377856;
  if (i2 < 23040) {
    int r = i2 / 160, c = i2 - r * 160;
    wb[idx] = f2bf((r < 129 && c < 129) ? Wq[r * 129 + c] : 0.f);
    return;
  }
  i2 -= 23040;
  if (i2 < 23040) {
    int r = i2 / 160, c = i2 - r * 160;
    wb[idx] = f2bf((r < 129 && c < 129) ? Wo[r * 129 + c] : 0.f);
    return;
  }
  i2 -= 23040;
  if (i2 < 46080) {
    int r = i2 / 320, c = i2 - r * 320;
    float v = 0.f;
    if (r < 128) {
      if (c < 129) v = W1[r * 257 + c];
      else if (c >= 160 && c < 288) v = W1[r * 257 + (c - 31)];
    }
    wb[idx] = f2bf(v);
    return;
  }
  i2 -= 46080;
  if (i2 < 18432) {
    int r = i2 / 128, c = i2 - r * 128;
    wb[idx] = f2bf(r < 128 ? W2[r * 128 + c] : 0.f);
  }
}

// ---------------------------------------------------------------------------
// nf pack: gather [emb|ef|td]x5 fp32 -> bf16 [rows][KDP], zero-padded.
// ---------------------------------------------------------------------------
__global__ __launch_bounds__(256) void packnf_k(
    const float* __restrict__ emb, const float* __restrict__ ef,
    const float* __restrict__ td, u16* __restrict__ dst, int nofs, int rows)
{
  int idx = blockIdx.x * 256 + threadIdx.x;
  if (idx >= rows * 328) return;
  int nr = idx / 328, q = idx - nr * 328;
  const int n = nofs + nr;
  const int c0 = q * 4;
  u16 o[4];
#pragma unroll
  for (int i = 0; i < 4; ++i) {
    int c = c0 + i;
    float v = 0.f;
    if (c < KD_) {
      int j = c / 257, r = c - j * 257;
      int base = (n * 5 + j) << 7;
      v = (r < 128) ? emb[base + r] : (r < 256) ? ef[base + r - 128] : td[n * 5 + j];
    }
    o[i] = f2bf(v);
  }
  *(uint2*)&dst[(size_t)nr * KDP + c0] = *(const uint2*)o;
}

// ---------------------------------------------------------------------------
// Unified bf16 MFMA GEMM. BM=64 rows, BN=144 cols per block, 256 thr.
// GA=0: A bf16 row-major, counted-vmcnt pipeline (3-deep W, 2-deep A regs).
// GA=1: A=[emb f32 [n][128] | td | 0]; conservative waits.
// GA=2: A=[a1 bf16 [n][160] (ksteps 0-4) | emb f32 [n][128] (ksteps 5-8) | 0].
// ZF: zero-fill output cols [N0,144) (only valid when !DUAL, OM0==1).
// ---------------------------------------------------------------------------
template<int GA, bool RELU, int OM0, int OM1, bool DUAL, bool ZF = false>
__global__ __launch_bounds__(256) void gmm_k(
    int nK, int Kw, int nch,
    const void* __restrict__ A, int ast,
    const float* __restrict__ g1, const float* __restrict__ g2,
    const u16* __restrict__ Wb,
    const float* __restrict__ b0, void* __restrict__ out0, int ost0, int N0,
    const float* __restrict__ b1, void* __restrict__ out1, int ost1,
    float scale)
{
  __shared__ u16 Ws_[3][9 * 512];
  const int t = threadIdx.x, lane = t & 63, w = t >> 6;
  const int lrow = lane & 15, lk = lane >> 4;
  const int bid = blockIdx.x;
  const int x = bid / nch, colh = bid - x * nch;
  const int n0 = x * 64;
  const int colofs = colh * 144;
  const int drow = lane >> 2, dseg = lane & 3;
  const int arow = n0 + w * 16 + lrow;

  f4_t acc[9];
#pragma unroll
  for (int ct = 0; ct < 9; ++ct) acc[ct] = (f4_t){0.f, 0.f, 0.f, 0.f};

  bf8_t afE, afO, dE, dO;
  float rE[8], rO[8];

  auto issueR = [&](int kst, float (&r)[8]) {    // GA==1
    const int cb = kst * 32 + lk * 8;
#pragma unroll
    for (int i = 0; i < 8; ++i) {
      int c = cb + i;
      uintptr_t pa = (uintptr_t)((const float*)A + (arow << 7) + c);
      uintptr_t pt = (uintptr_t)(g2 ? (g2 + arow) : (const float*)A);
      uintptr_t sel = (c < 128) ? pa : pt;
      float v = *(const float*)sel;
      r[i] = (c < 128) ? v : ((c == 128 && g2) ? v : 0.f);
    }
  };
  auto cvt8 = [&](const float (&r)[8]) -> bf8_t {
    union { bf8_t v; u32 u[4]; } xx;
#pragma unroll
    for (int i = 0; i < 4; ++i) xx.u[i] = pack2(r[2 * i], r[2 * i + 1]);
    return xx.v;
  };
  auto loadAf = [&](int kst) -> bf8_t {
    return *(const bf8_t*)((const u16*)A + (size_t)arow * ast + kst * 32 + lk * 8);
  };
  auto issue2 = [&](int kst, bf8_t& d, float (&r)[8]) {
    if (GA == 1) { issueR(kst, r); return; }
    if (kst < 5) { d = loadAf(kst); }
    else if (kst < 9) {
      const float* p = g1 + (size_t)arow * 128 + (kst - 5) * 32 + lk * 8;
      *(float4*)&r[0] = *(const float4*)p;
      *(float4*)&r[4] = *(const float4*)(p + 4);
    }
  };
  auto finish2 = [&](int kst, bf8_t& d, float (&r)[8]) -> bf8_t {
    if (GA == 1) return cvt8(r);
    if (kst < 5) return d;
    if (kst < 9) return cvt8(r);
    bf8_t z = {0, 0, 0, 0, 0, 0, 0, 0};
    return z;
  };
  auto dmaW = [&](int kst, u16* wbuf) {
    const int c0 = kst * 32;
#pragma unroll
    for (int si = 0; si < 3; ++si) {
      int s = w + si * 4;            // wave-uniform
      if (s < 9) {
        int rr = colofs + s * 16 + drow;
        int sseg = (dseg ^ (rr >> 1)) & 3;
        gload16(&Wb[(size_t)rr * Kw + c0 + sseg * 8], wbuf + s * 512);
      }
    }
  };
  auto compute = [&](bf8_t af, const u16* wsb) {
#pragma unroll
    for (int ct = 0; ct < 9; ++ct) {
      bf8_t bf = *(const bf8_t*)&wsb[swz8(ct * 16 + lrow, lk)];
      acc[ct] = MFMA16(af, bf, acc[ct]);
    }
  };

  if constexpr (GA == 0) {
    u16 *wa = Ws_[0], *wbuf = Ws_[1], *wc = Ws_[2];
    afE = loadAf(0);
    dmaW(0, wa);
    if (nK > 1) { afO = loadAf(1); dmaW(1, wbuf); }
    if (nK > 1) { WAIT_VM4(); } else { WAIT_VM0(); }
    __builtin_amdgcn_s_barrier();
    int k = 0;
    while (true) {
      if (k + 2 < nK) dmaW(k + 2, wc);
      compute(afE, wa);
      if (k + 2 < nK) afE = loadAf(k + 2);
      if (k + 1 >= nK) break;
      if (k + 2 < nK) { WAIT_VM4(); } else { WAIT_VM0(); }
      __builtin_amdgcn_s_barrier();
      { u16* tp = wa; wa = wbuf; wbuf = wc; wc = tp; }
      ++k;
      if (k + 2 < nK) dmaW(k + 2, wc);
      compute(afO, wa);
      if (k + 2 < nK) afO = loadAf(k + 2);
      if (k + 1 >= nK) break;
      if (k + 2 < nK) { WAIT_VM4(); } else { WAIT_VM0(); }
      __builtin_amdgcn_s_barrier();
      { u16* tp = wa; wa = wbuf; wbuf = wc; wc = tp; }
      ++k;
    }
  } else {
    issue2(0, dE, rE);
    dmaW(0, Ws_[0]);
    WAIT_VM0();
    afE = finish2(0, dE, rE);
    __builtin_amdgcn_s_barrier();
    int cur = 0, k = 0;
    while (true) {
      if (k + 1 < nK) { issue2(k + 1, dO, rO); dmaW(k + 1, Ws_[cur ^ 1]); }
      compute(afE, Ws_[cur]);
      if (k + 1 >= nK) break;
      WAIT_VM0();
      afO = finish2(k + 1, dO, rO);
      __builtin_amdgcn_s_barrier();
      cur ^= 1; ++k;
      if (k + 1 < nK) { issue2(k + 1, dE, rE); dmaW(k + 1, Ws_[cur ^ 1]); }
      compute(afO, Ws_[cur]);
      if (k + 1 >= nK) break;
      WAIT_VM0();
      afE = finish2(k + 1, dE, rE);
      __builtin_amdgcn_s_barrier();
      cur ^= 1; ++k;
    }
  }

  // epilogue
#pragma unroll
  for (int ct = 0; ct < 9; ++ct) {
    const int col = colofs + ct * 16 + lrow;
#pragma unroll
    for (int r = 0; r < 4; ++r) {
      const int n = n0 + w * 16 + lk * 4 + r;
      float v = acc[ct][r];
      if (col < N0) {
        v = (v + b0[col]) * scale;
        if (RELU) v = fmaxf(v, 0.f);
        if (OM0 == 0)      ((float*)out0)[(size_t)n * ost0 + col] = v;
        else if (OM0 == 1) ((u16*)out0)[(size_t)n * ost0 + col] = f2bf(v);
        else               ((u16*)out0)[(size_t)col * ost0 + n] = f2bf(v);
      } else if (DUAL) {
        int o = col - N0;
        if (o < 129) {
          v = (v + b1[o]) * scale;
          if (RELU) v = fmaxf(v, 0.f);
          if (OM1 == 0)      ((float*)out1)[(size_t)n * ost1 + o] = v;
          else if (OM1 == 1) ((u16*)out1)[(size_t)n * ost1 + o] = f2bf(v);
          else               ((u16*)out1)[(size_t)o * ost1 + n] = f2bf(v);
        }
      } else if (ZF && col < 144) {
        if (OM0 == 1) ((u16*)out0)[(size_t)n * ost0 + col] = 0;
      }
    }
  }
}

// ---------------------------------------------------------------------------
// i=0 attention: per batch b, 5 queries x 5 keys, dim 129 (bf16 in/out).
// ---------------------------------------------------------------------------
__global__ __launch_bounds__(256) void attn0_k(
    const u16* __restrict__ qp, const u16* __restrict__ kp,
    const u16* __restrict__ vp, u16* __restrict__ o0b)
{
  __shared__ float qs[4][5][SQ_], ks[4][5][SQ_], vs[4][5][SQ_];
  __shared__ float ps[4][5][8];
  const int t = threadIdx.x;
  const int bbase = blockIdx.x * 4;
  for (int idx = t; idx < 4 * 5 * 33; idx += 256) {
    int bl = idx / 165;
    int rem = idx - bl * 165;
    int row = rem / 33;
    int g = rem - row * 33;
    int n = (bbase + bl) * 5 + row;
    int d0 = g * 4;
    uint2 uq = *(const uint2*)&qp[(size_t)n * 160 + d0];
    uint2 uk = *(const uint2*)&kp[(size_t)n * 160 + d0];
    uint2 uv = *(const uint2*)&vp[(size_t)n * 160 + d0];
    u16 eq[4] = {(u16)uq.x, (u16)(uq.x >> 16), (u16)uq.y, (u16)(uq.y >> 16)};
    u16 ek[4] = {(u16)uk.x, (u16)(uk.x >> 16), (u16)uk.y, (u16)(uk.y >> 16)};
    u16 ev[4] = {(u16)uv.x, (u16)(uv.x >> 16), (u16)uv.y, (u16)(uv.y >> 16)};
#pragma unroll
    for (int i = 0; i < 4; ++i) {
      int d = d0 + i;
      bool ok = d < QD_;
      qs[bl][row][d] = ok ? bf2f(eq[i]) : 0.f;
      ks[bl][row][d] = ok ? bf2f(ek[i]) : 0.f;
      vs[bl][row][d] = ok ? bf2f(ev[i]) : 0.f;
    }
  }
  __syncthreads();
  const int w = t >> 6, lane = t & 63;
  if (lane < 25) {
    int qq = lane / 5, kk = lane - (lane / 5) * 5;
    float s = 0.f;
    for (int c = 0; c < SQ_; c += 4) {
      float4 qv = *(const float4*)&qs[w][qq][c];
      float4 kv = *(const float4*)&ks[w][kk][c];
      s += qv.x * kv.x + qv.y * kv.y + qv.z * kv.z + qv.w * kv.w;
    }
    ps[w][qq][kk] = s;
  }
  __syncthreads();
  if (lane < 5) {
    float m = -1e30f;
#pragma unroll
    for (int k = 0; k < 5; ++k) m = fmaxf(m, ps[w][lane][k]);
    float l = 0.f; float e[5];
#pragma unroll
    for (int k = 0; k < 5; ++k) { e[k] = __expf(ps[w][lane][k] - m); l += e[k]; }
    float inv = 1.f / l;
#pragma unroll
    for (int k = 0; k < 5; ++k) ps[w][lane][k] = e[k] * inv;
  }
  __syncthreads();
  for (int d = lane; d < 160; d += 64) {
#pragma unroll
    for (int qq = 0; qq < 5; ++qq) {
      float o = 0.f;
      if (d < QD_) {
#pragma unroll
        for (int k = 0; k < 5; ++k) o += ps[w][qq][k] * vs[w][k][d];
      }
      o0b[(size_t)((bbase + w) * 5 + qq) * 160 + d] = f2bf(o);
    }
  }
}

// ---------------------------------------------------------------------------
// i=1 MFMA flash attention, 32x32x16 MFMA (halves LDS reads per FLOP).
// QB=128 q-rows, 4 waves x 32 q-rows, KVB=64, NSPLIT=8, exp2 domain,
// gated defer-max, per-lane l partials. LDS 76 KB -> 2 blocks/CU.
// A/B frag: row/col=l&31, k=(l>>5)*8+i. C/D: col=l&31,
// row=(reg&3)+8*(reg>>2)+4*(l>>5).
// ---------------------------------------------------------------------------
#define QB   128
#define KVB  64
#define NSPLIT 8
#define NT   ((B_ / NSPLIT) / KVB)    // 16
__global__ __launch_bounds__(256, 2) void flashm_k(
    const u16* __restrict__ qp, const u16* __restrict__ kp,
    const u16* __restrict__ vpT, float* __restrict__ oacc,
    float* __restrict__ marr, float* __restrict__ larr)
{
  __shared__ u16 Ks[2][5 * 2048];   // [buf][dim-subtile][64 keys][32] swz8
  __shared__ u16 Vs[2 * 5120];      // [k-subtile][160 d-rows][32] (rows>=144 junk)
  __shared__ u16 Ps[4 * 2048];      // per wave: [2 k-subtiles][32 q][32] swz8
  const int t = threadIdx.x, lane = t & 63, w = t >> 6;
  const int l31 = lane & 31, lh = lane >> 5;
  const int split = blockIdx.x & (NSPLIT - 1);
  const int q0 = (blockIdx.x >> 3) * QB;
  const int drow = lane >> 2, dseg = lane & 3;
  const int kbase = split * (B_ / NSPLIT);

  auto dmaK = [&](int k0, u16* kb) {
#pragma unroll
    for (int si = 0; si < 5; ++si) {
      int s = w + si * 4;            // 0..19
      int kst = s >> 2, rg = s & 3;
      int r = rg * 16 + drow;
      int sseg = (dseg ^ (r >> 1)) & 3;
      gload16(&kp[(size_t)(k0 + r) * QPAD + kst * 32 + sseg * 8],
              kb + kst * 2048 + rg * 512);
    }
  };
  auto dmaV = [&](int k0) {
#pragma unroll
    for (int si = 0; si < 5; ++si) {
      int s = w + si * 4;            // 0..19 -> 18 real segs (dups benign)
      if (s >= 18) s -= 18;
      int kst = (s >= 9) ? 1 : 0;
      int rg = s - kst * 9;
      int r = rg * 16 + drow;
      int sseg = (dseg ^ (r >> 1)) & 3;
      gload16(&vpT[(size_t)r * B_ + k0 + kst * 32 + sseg * 8],
              Vs + kst * 5120 + rg * 512);
    }
  };

  // Q fragments: 10 ksteps of 16
  bf8_t qf[10];
  {
    const u16* qrow = qp + (size_t)(q0 + w * 32 + l31) * QPAD;
#pragma unroll
    for (int kst = 0; kst < 10; ++kst)
      qf[kst] = *(const bf8_t*)(qrow + kst * 16 + lh * 8);
  }

  f16f acc[5];
#pragma unroll
  for (int ct = 0; ct < 5; ++ct)
#pragma unroll
    for (int j = 0; j < 16; ++j) acc[ct][j] = 0.f;
  float m_[16], l_[16];
#pragma unroll
  for (int r = 0; r < 16; ++r) { m_[r] = -1e30f; l_[r] = 0.f; }

  // P store addresses (u16 index); col k = l31, subtile1 at +1024
  int paddr[16];
#pragma unroll
  for (int r = 0; r < 16; ++r) {
    int q = (r & 3) + 8 * (r >> 2) + 4 * lh;
    paddr[r] = w * 2048 + (q << 5) + ((((l31 >> 3) ^ (q >> 1)) & 3) << 3) + (l31 & 7);
  }

  dmaK(kbase, Ks[0]);
  for (int tl = 0; tl < NT; ++tl) {
    const int k0 = kbase + tl * KVB;
    const int cur = tl & 1;
    dmaV(k0);
    const bool more = (tl + 1 < NT);
    if (more) dmaK(k0 + KVB, Ks[cur ^ 1]);
    if (more) { WAIT_VM10(); } else { WAIT_VM5(); }   // K(tl) landed
    __builtin_amdgcn_s_barrier();

    // QK^T: 10 ksteps x 2 key-tiles of 32
    f16f s0, s1;
#pragma unroll
    for (int j = 0; j < 16; ++j) { s0[j] = 0.f; s1[j] = 0.f; }
#pragma unroll
    for (int kst = 0; kst < 10; ++kst) {
      const int seg = ((kst & 1) << 1) + lh;
      bf8_t b0 = *(const bf8_t*)&Ks[cur][(kst >> 1) * 2048 + swz8(l31, seg)];
      bf8_t b1 = *(const bf8_t*)&Ks[cur][(kst >> 1) * 2048 + swz8(32 + l31, seg)];
      s0 = MFMA32(qf[kst], b0, s0);
      s1 = MFMA32(qf[kst], b1, s1);
    }

    // gated online softmax (16 q-rows/lane; reduce over 32 lanes only on fire)
    float lm[16];
    bool need = false;
#pragma unroll
    for (int r = 0; r < 16; ++r) {
      lm[r] = fmaxf(s0[r], s1[r]);
      need = need || (lm[r] > m_[r] + 8.f);
    }
    if (__any(need)) {
#pragma unroll
      for (int r = 0; r < 16; ++r) {
        float pm = lm[r];
#pragma unroll
        for (int mk = 1; mk <= 16; mk <<= 1) pm = fmaxf(pm, __shfl_xor(pm, mk));
        float mn = fmaxf(m_[r], pm);
        float cf = exp2_fast(m_[r] - mn);
        m_[r] = mn;
        l_[r] *= cf;
#pragma unroll
        for (int ct = 0; ct < 5; ++ct) acc[ct][r] *= cf;
      }
    }
#pragma unroll
    for (int r = 0; r < 16; ++r) {
      float p0 = exp2_fast(s0[r] - m_[r]);
      float p1 = exp2_fast(s1[r] - m_[r]);
      l_[r] += p0 + p1;
      u32 pk = cvtpk(p0, p1);
      Ps[paddr[r]] = (u16)pk;
      Ps[paddr[r] + 1024] = (u16)(pk >> 16);
    }
    WAIT_LGKM0();
    __builtin_amdgcn_sched_barrier(0);

    if (more) { WAIT_VM5(); } else { WAIT_VM0(); }   // V(tl) landed
    __builtin_amdgcn_s_barrier();

    // PV: 4 ksteps of 16 x 5 d-tiles of 32
#pragma unroll
    for (int kst = 0; kst < 4; ++kst) {
      const int seg = ((kst & 1) << 1) + lh;
      bf8_t a = *(const bf8_t*)&Ps[w * 2048 + (kst >> 1) * 1024 + swz8(l31, seg)];
#pragma unroll
      for (int ct = 0; ct < 5; ++ct) {
        bf8_t b = *(const bf8_t*)&Vs[(kst >> 1) * 5120 + swz8(ct * 32 + l31, seg)];
        acc[ct] = MFMA32(a, b, acc[ct]);
      }
    }
    __builtin_amdgcn_s_barrier();   // Vs/Ps free for next tile
  }

  // one-time l reduction across 32 lanes
#pragma unroll
  for (int r = 0; r < 16; ++r) {
#pragma unroll
    for (int mk = 1; mk <= 16; mk <<= 1) l_[r] += __shfl_xor(l_[r], mk);
  }

  // store unnormalized acc + m,l (m in log2 domain)
#pragma unroll
  for (int ct = 0; ct < 5; ++ct) {
    const int col = ct * 32 + l31;
    if (col < SQ_) {
#pragma unroll
      for (int r = 0; r < 16; ++r) {
        const int q = q0 + w * 32 + (r & 3) + 8 * (r >> 2) + 4 * lh;
        oacc[((size_t)split * B_ + q) * SQ_ + col] = acc[ct][r];
      }
    }
  }
  if (l31 == 0) {
#pragma unroll
    for (int r = 0; r < 16; ++r) {
      const int q = q0 + w * 32 + (r & 3) + 8 * (r >> 2) + 4 * lh;
      size_t i = (size_t)split * B_ + q;
      marr[i] = m_[r];
      larr[i] = l_[r];
    }
  }
}

// ---------------------------------------------------------------------------
// combine splits (log2-domain m) -> o1b bf16 [8192][160] (pads zeroed)
// ---------------------------------------------------------------------------
__global__ __launch_bounds__(256) void combine_k(
    const float* __restrict__ oacc, const float* __restrict__ marr,
    const float* __restrict__ larr, u16* __restrict__ o1b)
{
  int idx = blockIdx.x * 256 + threadIdx.x;
  if (idx >= B_ * 160) return;
  int n = idx / 160, d = idx - n * 160;
  float v = 0.f;
  if (d < QD_) {
    float m = -1e30f;
#pragma unroll
    for (int s = 0; s < NSPLIT; ++s) m = fmaxf(m, marr[s * B_ + n]);
    float l = 0.f, o = 0.f;
#pragma unroll
    for (int s = 0; s < NSPLIT; ++s) {
      float e = exp2_fast(marr[s * B_ + n] - m);
      l += larr[s * B_ + n] * e;
      o += oacc[((size_t)s * B_ + n) * SQ_ + d] * e;
    }
    v = o / l;
  }
  o1b[idx] = f2bf(v);
}

// ---------------------------------------------------------------------------
extern "C" void kernel_launch(void* const* d_in, const int* in_sizes, int n_in,
                              void* d_out, int out_size, void* d_ws, size_t ws_size,
                              hipStream_t stream)
{
  const float* emb0 = (const float*)d_in[0];
  const float* ef0  = (const float*)d_in[1];
  const float* td0  = (const float*)d_in[2];
  const float* emb1 = (const float*)d_in[3];
  const float* ef1  = (const float*)d_in[4];
  const float* td1  = (const float*)d_in[5];
  const float* emb2 = (const float*)d_in[6];
  const float* Wq = (const float*)d_in[7];  const float* bq = (const float*)d_in[8];
  const float* Wk = (const float*)d_in[9];  const float* bk = (const float*)d_in[10];
  const float* Wv = (const float*)d_in[11]; const float* bv = (const float*)d_in[12];
  const float* Wo = (const float*)d_in[13]; const float* bo = (const float*)d_in[14];
  const float* W1 = (const float*)d_in[15]; const float* b1 = (const float*)d_in[16];
  const float* W2 = (const float*)d_in[17]; const float* b2 = (const float*)d_in[18];
  float* out = (float*)d_out;

  char* ws = (char*)d_ws;
  // weights bf16 @0
  u16* wb   = (u16*)ws;
  u16* wkv  = wb;
  u16* wq_b = wb + 377856;
  u16* wo_b = wb + 400896;
  u16* w1_b = wb + 423936;
  u16* w2_b = wb + 470016;
  // i=0 (all bf16 [40960][160])
  u16*   kp0b = (u16*)(ws + 1048576);
  u16*   vp0b = (u16*)(ws + 14155776);
  u16*   qp0b = (u16*)(ws + 27262976);
  u16*   nfp  = (u16*)(ws + 44302336);     // [20480][1312] bf16 row-half pack
  u16*   o0b  = (u16*)(ws + 65929216);     // [40960][160]
  u16*   a1b0 = (u16*)(ws + 1048576);      // [40960][160] (overlays kp0b)
  u16*   h0   = (u16*)(ws + 24641536);     // [40960][128] (overlays qp0b tail)
  // i=1 (live only after i=0 fully drained)
  u16*   nf1p = (u16*)(ws + 1048576);      // [8192][1312]
  u16*   qp1b = (u16*)(ws + 22675456);     // [8192][160]
  u16*   kp1b = (u16*)(ws + 25296896);
  u16*   vp1T = (u16*)(ws + 27918336);     // [144][8192]
  u16*   o1b  = (u16*)(ws + 30277632);     // [8192][160]
  float* marr = (float*)(ws + 32899072);   // [8][8192]
  float* larr = (float*)(ws + 33161216);   // [8][8192]
  u16*   a1b1 = (u16*)(ws + 33423360);     // [8192][160]
  u16*   h1   = (u16*)(ws + 38141952);     // [8192][128]
  float* oacc = (float*)(ws + 40239104);   // [8][8192][132] f32

  const float scale = 0.08804509063256238f;            // 1/sqrt(129)
  const float scale2 = scale * 1.4426950408889634f;    // * log2e
  const int HROWS = 20480;

  convw_k<<<1908, 256, 0, stream>>>(Wq, Wk, Wv, Wo, W1, W2, wb);

  // ---- i = 0 -------------------------------------------------------------
  for (int h = 0; h < 2; ++h) {
    packnf_k<<<(HROWS * 328 + 255) / 256, 256, 0, stream>>>(
        emb0, ef0, td0, nfp, h * HROWS, HROWS);
    gmm_k<0, false, 1, 1, true><<<(HROWS / 64) * 2, 256, 0, stream>>>(
        41, KDP, 2, nfp, KDP, nullptr, nullptr, wkv,
        bk, kp0b + (size_t)h * HROWS * 160, 160, QD_,
        bv, vp0b + (size_t)h * HROWS * 160, 160, 1.f);
  }
  gmm_k<1, false, 1, 0, false><<<640, 256, 0, stream>>>(
      5, 160, 1, emb1, 0, nullptr, td1, wq_b,
      bq, qp0b, 160, QD_, nullptr, nullptr, 0, scale);
  attn0_k<<<B_ / 4, 256, 0, stream>>>(qp0b, kp0b, vp0b, o0b);
  // Wo -> a1b0 [.][160], zero-fill cols 129..143
  gmm_k<0, false, 1, 0, false, true><<<640, 256, 0, stream>>>(
      5, 160, 1, o0b, 160, nullptr, nullptr, wo_b,
      bo, a1b0, 160, QD_, nullptr, nullptr, 0, 1.f);
  // W1 relu -> h0: A = [a1b0 | emb1 f32], K=320
  gmm_k<2, true, 1, 0, false><<<640, 256, 0, stream>>>(
      10, 320, 1, a1b0, 160, emb1, nullptr, w1_b,
      b1, h0, 128, 128, nullptr, nullptr, 0, 1.f);
  gmm_k<0, false, 0, 0, false><<<640, 256, 0, stream>>>(
      4, 128, 1, h0, 128, nullptr, nullptr, w2_b,
      b2, out, 128, 128, nullptr, nullptr, 0, 1.f);

  // ---- i = 1 -------------------------------------------------------------
  packnf_k<<<(B_ * 328 + 255) / 256, 256, 0, stream>>>(
      emb1, ef1, td1, nf1p, 0, B_);
  hipMemsetAsync(qp1b, 0, 2621440, stream);
  hipMemsetAsync(kp1b, 0, 2621440, stream);
  hipMemsetAsync(vp1T, 0, 2359296, stream);
  gmm_k<0, false, 1, 2, true><<<(B_ / 64) * 2, 256, 0, stream>>>(
      41, KDP, 2, nf1p, KDP, nullptr, nullptr, wkv,
      bk, kp1b, QPAD, QD_, bv, vp1T, B_, 1.f);
  gmm_k<1, false, 1, 0, false><<<128, 256, 0, stream>>>(
      5, 160, 1, emb2, 0, nullptr, nullptr, wq_b,
      bq, qp1b, QPAD, QD_, nullptr, nullptr, 0, scale2);
  flashm_k<<<(B_ / QB) * NSPLIT, 256, 0, stream>>>(qp1b, kp1b, vp1T, oacc, marr, larr);
  combine_k<<<(B_ * 160 + 255) / 256, 256, 0, stream>>>(oacc, marr, larr, o1b);
  gmm_k<0, false, 1, 0, false, true><<<128, 256, 0, stream>>>(
      5, 160, 1, o1b, 160, nullptr, nullptr, wo_b,
      bo, a1b1, 160, QD_, nullptr, nullptr, 0, 1.f);
  gmm_k<2, true, 1, 0, false><<<128, 256, 0, stream>>>(
      10, 320, 1, a1b1, 160, emb2, nullptr, w1_b,
      b1, h1, 128, 128, nullptr, nullptr, 0, 1.f);
  gmm_k<0, false, 0, 0, false><<<128, 256, 0, stream>>>(
      4, 128, 1, h1, 128, nullptr, nullptr, w2_b,
      b2, out + (size_t)BK_ * D_, 128, 128, nullptr, nullptr, 0, 1.f);
}

// Round 15
// 404.369 us; speedup vs baseline: 1.0620x; 1.0620x over previous
//
#include <hip/hip_runtime.h>

#define B_   8192
#define K_   5
#define D_   128
#define QD_  129
#define KD_  1285
#define SQ_  132      // padded row stride (oacc, attn0 LDS)
#define BK_  40960    // B_*K_
#define QPAD 160      // bf16 k-dim padding (5 x 32)
#define VPAD 144      // bf16 out-dim padding (9 x 16)
#define KDP  1312     // KD_ padded to 41*32

typedef unsigned short u16;
typedef unsigned int   u32;
typedef __attribute__((ext_vector_type(8))) short bf8_t;
typedef __attribute__((ext_vector_type(4))) float f4_t;
typedef __attribute__((address_space(3))) u32 lds_u32;
typedef __attribute__((address_space(1))) const u32 glob_u32;

#define MFMA16(a, b, c) __builtin_amdgcn_mfma_f32_16x16x32_bf16(a, b, c, 0, 0, 0)

__device__ __forceinline__ u16 f2bf(float x) {
  u32 u = __float_as_uint(x);
  u = (u + 0x7fffu + ((u >> 16) & 1u)) >> 16;
  return (u16)u;
}
__device__ __forceinline__ float bf2f(u16 v) {
  return __uint_as_float((u32)v << 16);
}
__device__ __forceinline__ u32 pack2(float a, float b) {
  return (u32)f2bf(a) | ((u32)f2bf(b) << 16);
}
__device__ __forceinline__ float exp2_fast(float x) {
  float r; asm("v_exp_f32 %0, %1" : "=v"(r) : "v"(x)); return r;
}
__device__ __forceinline__ u32 cvtpk(float a, float b) {
  u32 r;
  asm("v_cvt_pk_bf16_f32 %0, %1, %2" : "=v"(r) : "v"(a), "v"(b));
  return r;
}
__device__ __forceinline__ int swz8(int row, int seg) {
  return (row << 5) + (((seg ^ (row >> 1)) & 3) << 3);
}
__device__ __forceinline__ void gload16(const u16* src, u16* ldsdst) {
  __builtin_amdgcn_global_load_lds((glob_u32*)src, (lds_u32*)ldsdst, 16, 0, 0);
}
#define WAIT_VM0() asm volatile("s_waitcnt vmcnt(0)" ::: "memory")
#define WAIT_VM3() asm volatile("s_waitcnt vmcnt(3)" ::: "memory")
#define WAIT_VM4() asm volatile("s_waitcnt vmcnt(4)" ::: "memory")
#define WAIT_VM6() asm volatile("s_waitcnt vmcnt(6)" ::: "memory")
#define WAIT_LGKM0() asm volatile("s_waitcnt lgkmcnt(0)" ::: "memory")

// ---------------------------------------------------------------------------
// One-time weight conversion fp32 -> bf16 with zero padding.
//   wkv [288][1312] @0        rows 0-128 Wk, 129-257 Wv
//   wq  [144][160]  @377856
//   wo  [144][160]  @400896
//   w1  [144][320]  @423936   (cols 0-128 = W1[:,0:129], 160-287 = W1[:,129:257])
//   w2  [144][128]  @470016   (end 488448)
// ---------------------------------------------------------------------------
__global__ __launch_bounds__(256) void convw_k(
    const float* __restrict__ Wq, const float* __restrict__ Wk,
    const float* __restrict__ Wv, const float* __restrict__ Wo,
    const float* __restrict__ W1, const float* __restrict__ W2,
    u16* __restrict__ wb)
{
  int idx = blockIdx.x * 256 + threadIdx.x;
  if (idx < 377856) {
    int r = idx / KDP, c = idx - r * KDP;
    float v = 0.f;
    if (c < KD_) {
      if (r < 129) v = Wk[r * KD_ + c];
      else if (r < 258) v = Wv[(r - 129) * KD_ + c];
    }
    wb[idx] = f2bf(v);
    return;
  }
  int i2 = idx - 377856;
  if (i2 < 23040) {
    int r = i2 / 160, c = i2 - r * 160;
    wb[idx] = f2bf((r < 129 && c < 129) ? Wq[r * 129 + c] : 0.f);
    return;
  }
  i2 -= 23040;
  if (i2 < 23040) {
    int r = i2 / 160, c = i2 - r * 160;
    wb[idx] = f2bf((r < 129 && c < 129) ? Wo[r * 129 + c] : 0.f);
    return;
  }
  i2 -= 23040;
  if (i2 < 46080) {
    int r = i2 / 320, c = i2 - r * 320;
    float v = 0.f;
    if (r < 128) {
      if (c < 129) v = W1[r * 257 + c];
      else if (c >= 160 && c < 288) v = W1[r * 257 + (c - 31)];
    }
    wb[idx] = f2bf(v);
    return;
  }
  i2 -= 46080;
  if (i2 < 18432) {
    int r = i2 / 128, c = i2 - r * 128;
    wb[idx] = f2bf(r < 128 ? W2[r * 128 + c] : 0.f);
  }
}

// ---------------------------------------------------------------------------
// nf pack: gather [emb|ef|td]x5 fp32 -> bf16 [rows][KDP], zero-padded.
// ---------------------------------------------------------------------------
__global__ __launch_bounds__(256) void packnf_k(
    const float* __restrict__ emb, const float* __restrict__ ef,
    const float* __restrict__ td, u16* __restrict__ dst, int nofs, int rows)
{
  int idx = blockIdx.x * 256 + threadIdx.x;
  if (idx >= rows * 328) return;
  int nr = idx / 328, q = idx - nr * 328;
  const int n = nofs + nr;
  const int c0 = q * 4;
  u16 o[4];
#pragma unroll
  for (int i = 0; i < 4; ++i) {
    int c = c0 + i;
    float v = 0.f;
    if (c < KD_) {
      int j = c / 257, r = c - j * 257;
      int base = (n * 5 + j) << 7;
      v = (r < 128) ? emb[base + r] : (r < 256) ? ef[base + r - 128] : td[n * 5 + j];
    }
    o[i] = f2bf(v);
  }
  *(uint2*)&dst[(size_t)nr * KDP + c0] = *(const uint2*)o;
}

// ---------------------------------------------------------------------------
// Unified bf16 MFMA GEMM. BM=64 rows, BN=144 cols per block, 256 thr.
// GA=0: A bf16 row-major, counted-vmcnt pipeline (3-deep W, 2-deep A regs).
// GA=1: A=[emb f32 [n][128] | td | 0]; conservative waits.
// GA=2: A=[a1 bf16 [n][160] (ksteps 0-4) | emb f32 [n][128] (ksteps 5-8) | 0].
// ZF: zero-fill output cols [N0,144) (only valid when !DUAL, OM0==1).
// ---------------------------------------------------------------------------
template<int GA, bool RELU, int OM0, int OM1, bool DUAL, bool ZF = false>
__global__ __launch_bounds__(256) void gmm_k(
    int nK, int Kw, int nch,
    const void* __restrict__ A, int ast,
    const float* __restrict__ g1, const float* __restrict__ g2,
    const u16* __restrict__ Wb,
    const float* __restrict__ b0, void* __restrict__ out0, int ost0, int N0,
    const float* __restrict__ b1, void* __restrict__ out1, int ost1,
    float scale)
{
  __shared__ u16 Ws_[3][9 * 512];
  const int t = threadIdx.x, lane = t & 63, w = t >> 6;
  const int lrow = lane & 15, lk = lane >> 4;
  const int bid = blockIdx.x;
  const int x = bid / nch, colh = bid - x * nch;
  const int n0 = x * 64;
  const int colofs = colh * 144;
  const int drow = lane >> 2, dseg = lane & 3;
  const int arow = n0 + w * 16 + lrow;

  f4_t acc[9];
#pragma unroll
  for (int ct = 0; ct < 9; ++ct) acc[ct] = (f4_t){0.f, 0.f, 0.f, 0.f};

  bf8_t afE, afO, dE, dO;
  float rE[8], rO[8];

  auto issueR = [&](int kst, float (&r)[8]) {    // GA==1
    const int cb = kst * 32 + lk * 8;
#pragma unroll
    for (int i = 0; i < 8; ++i) {
      int c = cb + i;
      uintptr_t pa = (uintptr_t)((const float*)A + (arow << 7) + c);
      uintptr_t pt = (uintptr_t)(g2 ? (g2 + arow) : (const float*)A);
      uintptr_t sel = (c < 128) ? pa : pt;
      float v = *(const float*)sel;
      r[i] = (c < 128) ? v : ((c == 128 && g2) ? v : 0.f);
    }
  };
  auto cvt8 = [&](const float (&r)[8]) -> bf8_t {
    union { bf8_t v; u32 u[4]; } xx;
#pragma unroll
    for (int i = 0; i < 4; ++i) xx.u[i] = pack2(r[2 * i], r[2 * i + 1]);
    return xx.v;
  };
  auto loadAf = [&](int kst) -> bf8_t {
    return *(const bf8_t*)((const u16*)A + (size_t)arow * ast + kst * 32 + lk * 8);
  };
  auto issue2 = [&](int kst, bf8_t& d, float (&r)[8]) {
    if (GA == 1) { issueR(kst, r); return; }
    if (kst < 5) { d = loadAf(kst); }
    else if (kst < 9) {
      const float* p = g1 + (size_t)arow * 128 + (kst - 5) * 32 + lk * 8;
      *(float4*)&r[0] = *(const float4*)p;
      *(float4*)&r[4] = *(const float4*)(p + 4);
    }
  };
  auto finish2 = [&](int kst, bf8_t& d, float (&r)[8]) -> bf8_t {
    if (GA == 1) return cvt8(r);
    if (kst < 5) return d;
    if (kst < 9) return cvt8(r);
    bf8_t z = {0, 0, 0, 0, 0, 0, 0, 0};
    return z;
  };
  auto dmaW = [&](int kst, u16* wbuf) {
    const int c0 = kst * 32;
#pragma unroll
    for (int si = 0; si < 3; ++si) {
      int s = w + si * 4;            // wave-uniform
      if (s < 9) {
        int rr = colofs + s * 16 + drow;
        int sseg = (dseg ^ (rr >> 1)) & 3;
        gload16(&Wb[(size_t)rr * Kw + c0 + sseg * 8], wbuf + s * 512);
      }
    }
  };
  auto compute = [&](bf8_t af, const u16* wsb) {
#pragma unroll
    for (int ct = 0; ct < 9; ++ct) {
      bf8_t bf = *(const bf8_t*)&wsb[swz8(ct * 16 + lrow, lk)];
      acc[ct] = MFMA16(af, bf, acc[ct]);
    }
  };

  if constexpr (GA == 0) {
    u16 *wa = Ws_[0], *wbuf = Ws_[1], *wc = Ws_[2];
    afE = loadAf(0);
    dmaW(0, wa);
    if (nK > 1) { afO = loadAf(1); dmaW(1, wbuf); }
    if (nK > 1) { WAIT_VM4(); } else { WAIT_VM0(); }
    __builtin_amdgcn_s_barrier();
    int k = 0;
    while (true) {
      if (k + 2 < nK) dmaW(k + 2, wc);
      compute(afE, wa);
      if (k + 2 < nK) afE = loadAf(k + 2);
      if (k + 1 >= nK) break;
      if (k + 2 < nK) { WAIT_VM4(); } else { WAIT_VM0(); }
      __builtin_amdgcn_s_barrier();
      { u16* tp = wa; wa = wbuf; wbuf = wc; wc = tp; }
      ++k;
      if (k + 2 < nK) dmaW(k + 2, wc);
      compute(afO, wa);
      if (k + 2 < nK) afO = loadAf(k + 2);
      if (k + 1 >= nK) break;
      if (k + 2 < nK) { WAIT_VM4(); } else { WAIT_VM0(); }
      __builtin_amdgcn_s_barrier();
      { u16* tp = wa; wa = wbuf; wbuf = wc; wc = tp; }
      ++k;
    }
  } else {
    issue2(0, dE, rE);
    dmaW(0, Ws_[0]);
    WAIT_VM0();
    afE = finish2(0, dE, rE);
    __builtin_amdgcn_s_barrier();
    int cur = 0, k = 0;
    while (true) {
      if (k + 1 < nK) { issue2(k + 1, dO, rO); dmaW(k + 1, Ws_[cur ^ 1]); }
      compute(afE, Ws_[cur]);
      if (k + 1 >= nK) break;
      WAIT_VM0();
      afO = finish2(k + 1, dO, rO);
      __builtin_amdgcn_s_barrier();
      cur ^= 1; ++k;
      if (k + 1 < nK) { issue2(k + 1, dE, rE); dmaW(k + 1, Ws_[cur ^ 1]); }
      compute(afO, Ws_[cur]);
      if (k + 1 >= nK) break;
      WAIT_VM0();
      afE = finish2(k + 1, dE, rE);
      __builtin_amdgcn_s_barrier();
      cur ^= 1; ++k;
    }
  }

  // epilogue
#pragma unroll
  for (int ct = 0; ct < 9; ++ct) {
    const int col = colofs + ct * 16 + lrow;
#pragma unroll
    for (int r = 0; r < 4; ++r) {
      const int n = n0 + w * 16 + lk * 4 + r;
      float v = acc[ct][r];
      if (col < N0) {
        v = (v + b0[col]) * scale;
        if (RELU) v = fmaxf(v, 0.f);
        if (OM0 == 0)      ((float*)out0)[(size_t)n * ost0 + col] = v;
        else if (OM0 == 1) ((u16*)out0)[(size_t)n * ost0 + col] = f2bf(v);
        else               ((u16*)out0)[(size_t)col * ost0 + n] = f2bf(v);
      } else if (DUAL) {
        int o = col - N0;
        if (o < 129) {
          v = (v + b1[o]) * scale;
          if (RELU) v = fmaxf(v, 0.f);
          if (OM1 == 0)      ((float*)out1)[(size_t)n * ost1 + o] = v;
          else if (OM1 == 1) ((u16*)out1)[(size_t)n * ost1 + o] = f2bf(v);
          else               ((u16*)out1)[(size_t)o * ost1 + n] = f2bf(v);
        }
      } else if (ZF && col < 144) {
        if (OM0 == 1) ((u16*)out0)[(size_t)n * ost0 + col] = 0;
      }
    }
  }
}

// ---------------------------------------------------------------------------
// i=0 attention: per batch b, 5 queries x 5 keys, dim 129 (bf16 in/out).
// ---------------------------------------------------------------------------
__global__ __launch_bounds__(256) void attn0_k(
    const u16* __restrict__ qp, const u16* __restrict__ kp,
    const u16* __restrict__ vp, u16* __restrict__ o0b)
{
  __shared__ float qs[4][5][SQ_], ks[4][5][SQ_], vs[4][5][SQ_];
  __shared__ float ps[4][5][8];
  const int t = threadIdx.x;
  const int bbase = blockIdx.x * 4;
  for (int idx = t; idx < 4 * 5 * 33; idx += 256) {
    int bl = idx / 165;
    int rem = idx - bl * 165;
    int row = rem / 33;
    int g = rem - row * 33;
    int n = (bbase + bl) * 5 + row;
    int d0 = g * 4;
    uint2 uq = *(const uint2*)&qp[(size_t)n * 160 + d0];
    uint2 uk = *(const uint2*)&kp[(size_t)n * 160 + d0];
    uint2 uv = *(const uint2*)&vp[(size_t)n * 160 + d0];
    u16 eq[4] = {(u16)uq.x, (u16)(uq.x >> 16), (u16)uq.y, (u16)(uq.y >> 16)};
    u16 ek[4] = {(u16)uk.x, (u16)(uk.x >> 16), (u16)uk.y, (u16)(uk.y >> 16)};
    u16 ev[4] = {(u16)uv.x, (u16)(uv.x >> 16), (u16)uv.y, (u16)(uv.y >> 16)};
#pragma unroll
    for (int i = 0; i < 4; ++i) {
      int d = d0 + i;
      bool ok = d < QD_;
      qs[bl][row][d] = ok ? bf2f(eq[i]) : 0.f;
      ks[bl][row][d] = ok ? bf2f(ek[i]) : 0.f;
      vs[bl][row][d] = ok ? bf2f(ev[i]) : 0.f;
    }
  }
  __syncthreads();
  const int w = t >> 6, lane = t & 63;
  if (lane < 25) {
    int qq = lane / 5, kk = lane - (lane / 5) * 5;
    float s = 0.f;
    for (int c = 0; c < SQ_; c += 4) {
      float4 qv = *(const float4*)&qs[w][qq][c];
      float4 kv = *(const float4*)&ks[w][kk][c];
      s += qv.x * kv.x + qv.y * kv.y + qv.z * kv.z + qv.w * kv.w;
    }
    ps[w][qq][kk] = s;
  }
  __syncthreads();
  if (lane < 5) {
    float m = -1e30f;
#pragma unroll
    for (int k = 0; k < 5; ++k) m = fmaxf(m, ps[w][lane][k]);
    float l = 0.f; float e[5];
#pragma unroll
    for (int k = 0; k < 5; ++k) { e[k] = __expf(ps[w][lane][k] - m); l += e[k]; }
    float inv = 1.f / l;
#pragma unroll
    for (int k = 0; k < 5; ++k) ps[w][lane][k] = e[k] * inv;
  }
  __syncthreads();
  for (int d = lane; d < 160; d += 64) {
#pragma unroll
    for (int qq = 0; qq < 5; ++qq) {
      float o = 0.f;
      if (d < QD_) {
#pragma unroll
        for (int k = 0; k < 5; ++k) o += ps[w][qq][k] * vs[w][k][d];
      }
      o0b[(size_t)((bbase + w) * 5 + qq) * 160 + d] = f2bf(o);
    }
  }
}

// ---------------------------------------------------------------------------
// i=1 MFMA flash attention — PROVEN r13 structure (16x16, 512 thr, 8 waves,
// gated defer-max, per-lane l partials, exp2 domain). Only change vs r13:
// oacc stored as bf16 (halves split-partial HBM traffic).
// ---------------------------------------------------------------------------
#define QB   128
#define KVB  64
#define NSPLIT 8
#define NT   ((B_ / NSPLIT) / KVB)    // 16
__global__ __launch_bounds__(512, 4) void flashm_k(
    const u16* __restrict__ qp, const u16* __restrict__ kp,
    const u16* __restrict__ vpT, u16* __restrict__ oacc,
    float* __restrict__ marr, float* __restrict__ larr)
{
  __shared__ u16 Ks[2][5 * 2048];   // [buf][kst][64][32] swz8
  __shared__ u16 Vs[2 * 4608];      // [kst2][144][32] swz8
  __shared__ u16 Ps[2 * 4096];      // [kst2][128][32] swz8
  const int t = threadIdx.x, lane = t & 63, w = t >> 6;
  const int lrow = lane & 15, lk = lane >> 4;
  const int split = blockIdx.x & (NSPLIT - 1);
  const int q0 = (blockIdx.x >> 3) * QB;
  const int drow = lane >> 2, dseg = lane & 3;
  const int kbase = split * (B_ / NSPLIT);

  auto dmaK = [&](int k0, u16* kb) {
#pragma unroll
    for (int si = 0; si < 3; ++si) {
      int s = w + si * 8;
      if (s >= 20) s -= 20;
      int kst = s >> 2, rg = s & 3;
      int r = rg * 16 + drow;
      int sseg = (dseg ^ (r >> 1)) & 3;
      gload16(&kp[(size_t)(k0 + r) * QPAD + kst * 32 + sseg * 8],
              kb + kst * 2048 + rg * 512);
    }
  };
  auto dmaV = [&](int k0) {
#pragma unroll
    for (int si = 0; si < 3; ++si) {
      int s = w + si * 8;
      if (s >= 18) s -= 18;
      int kst = (s >= 9) ? 1 : 0;
      int rg = s - kst * 9;
      int r = rg * 16 + drow;
      int sseg = (dseg ^ (r >> 1)) & 3;
      gload16(&vpT[(size_t)r * B_ + k0 + kst * 32 + sseg * 8],
              Vs + kst * 4608 + rg * 512);
    }
  };

  bf8_t qf[5];
  {
    const u16* qrow = qp + (size_t)(q0 + w * 16 + lrow) * QPAD;
#pragma unroll
    for (int kst = 0; kst < 5; ++kst)
      qf[kst] = *(const bf8_t*)(qrow + kst * 32 + lk * 8);
  }

  f4_t acc[9];
#pragma unroll
  for (int ct = 0; ct < 9; ++ct) acc[ct] = (f4_t){0.f, 0.f, 0.f, 0.f};
  float m_[4] = {-1e30f, -1e30f, -1e30f, -1e30f};
  float l_[4] = {0.f, 0.f, 0.f, 0.f};   // per-lane partials (reduced at end)

  dmaK(kbase, Ks[0]);
  for (int tl = 0; tl < NT; ++tl) {
    const int k0 = kbase + tl * KVB;
    const int cur = tl & 1;
    dmaV(k0);
    const bool more = (tl + 1 < NT);
    if (more) dmaK(k0 + KVB, Ks[cur ^ 1]);
    if (more) { WAIT_VM6(); } else { WAIT_VM3(); }   // K(tl) landed
    __builtin_amdgcn_s_barrier();

    // QK^T (exp2-domain scores): 5 ksts x 4 col-tiles
    f4_t s4[4];
#pragma unroll
    for (int ct = 0; ct < 4; ++ct) s4[ct] = (f4_t){0.f, 0.f, 0.f, 0.f};
#pragma unroll
    for (int kst = 0; kst < 5; ++kst) {
#pragma unroll
      for (int ct = 0; ct < 4; ++ct) {
        bf8_t b = *(const bf8_t*)&Ks[cur][kst * 2048 + swz8(ct * 16 + lrow, lk)];
        s4[ct] = MFMA16(qf[kst], b, s4[ct]);
      }
    }

    // gated online softmax
    float lmax[4];
#pragma unroll
    for (int r = 0; r < 4; ++r)
      lmax[r] = fmaxf(fmaxf(s4[0][r], s4[1][r]), fmaxf(s4[2][r], s4[3][r]));
    bool need = (lmax[0] > m_[0] + 8.f) || (lmax[1] > m_[1] + 8.f) ||
                (lmax[2] > m_[2] + 8.f) || (lmax[3] > m_[3] + 8.f);
    if (__any(need)) {
      float cf[4];
#pragma unroll
      for (int r = 0; r < 4; ++r) {
        float pm = lmax[r];
#pragma unroll
        for (int mk = 1; mk <= 8; mk <<= 1) pm = fmaxf(pm, __shfl_xor(pm, mk));
        float mn = fmaxf(m_[r], pm);
        cf[r] = exp2_fast(m_[r] - mn);
        m_[r] = mn;
        l_[r] *= cf[r];
      }
#pragma unroll
      for (int ct = 0; ct < 9; ++ct) {
#pragma unroll
        for (int r = 0; r < 4; ++r) acc[ct][r] *= cf[r];
      }
    }
    float pv[4][4];
#pragma unroll
    for (int ct = 0; ct < 4; ++ct) {
#pragma unroll
      for (int r = 0; r < 4; ++r) {
        pv[ct][r] = exp2_fast(s4[ct][r] - m_[r]);
        l_[r] += pv[ct][r];
      }
    }
#pragma unroll
    for (int half = 0; half < 2; ++half) {
#pragma unroll
      for (int r = 0; r < 4; ++r) {
        u32 pk = cvtpk(pv[half * 2][r], pv[half * 2 + 1][r]);
        const int q = w * 16 + lk * 4 + r;
        const int c0 = lrow, c1 = 16 + lrow;
        const int base = half * 4096 + (q << 5);
        Ps[base + ((((c0 >> 3) ^ (q >> 1)) & 3) << 3) + (c0 & 7)] = (u16)pk;
        Ps[base + ((((c1 >> 3) ^ (q >> 1)) & 3) << 3) + (c1 & 7)] = (u16)(pk >> 16);
      }
    }
    WAIT_LGKM0();
    __builtin_amdgcn_sched_barrier(0);

    if (more) { WAIT_VM3(); } else { WAIT_VM0(); }   // V(tl) landed
    __builtin_amdgcn_s_barrier();

    // PV: 2 ksts x 9 col-tiles
#pragma unroll
    for (int kst = 0; kst < 2; ++kst) {
      bf8_t a = *(const bf8_t*)&Ps[kst * 4096 + swz8(w * 16 + lrow, lk)];
#pragma unroll
      for (int ct = 0; ct < 9; ++ct) {
        bf8_t b = *(const bf8_t*)&Vs[kst * 4608 + swz8(ct * 16 + lrow, lk)];
        acc[ct] = MFMA16(a, b, acc[ct]);
      }
    }
    __builtin_amdgcn_s_barrier();   // Vs/Ps free for next tile
  }

  // one-time l reduction across the 16-lane lrow group
#pragma unroll
  for (int r = 0; r < 4; ++r) {
#pragma unroll
    for (int mk = 1; mk <= 8; mk <<= 1) l_[r] += __shfl_xor(l_[r], mk);
  }

  // store unnormalized acc (bf16) + m,l (m in log2 domain)
#pragma unroll
  for (int ct = 0; ct < 9; ++ct) {
    const int col = ct * 16 + lrow;
    if (col < SQ_) {
#pragma unroll
      for (int r = 0; r < 4; ++r)
        oacc[((size_t)split * B_ + q0 + w * 16 + lk * 4 + r) * SQ_ + col] = f2bf(acc[ct][r]);
    }
  }
  if (lrow == 0) {
#pragma unroll
    for (int r = 0; r < 4; ++r) {
      size_t i = (size_t)split * B_ + q0 + w * 16 + lk * 4 + r;
      marr[i] = m_[r];
      larr[i] = l_[r];
    }
  }
}

// ---------------------------------------------------------------------------
// combine splits (log2-domain m, bf16 oacc) -> o1b bf16 [8192][160]
// ---------------------------------------------------------------------------
__global__ __launch_bounds__(256) void combine_k(
    const u16* __restrict__ oacc, const float* __restrict__ marr,
    const float* __restrict__ larr, u16* __restrict__ o1b)
{
  int idx = blockIdx.x * 256 + threadIdx.x;
  if (idx >= B_ * 160) return;
  int n = idx / 160, d = idx - n * 160;
  float v = 0.f;
  if (d < QD_) {
    float m = -1e30f;
#pragma unroll
    for (int s = 0; s < NSPLIT; ++s) m = fmaxf(m, marr[s * B_ + n]);
    float l = 0.f, o = 0.f;
#pragma unroll
    for (int s = 0; s < NSPLIT; ++s) {
      float e = exp2_fast(marr[s * B_ + n] - m);
      l += larr[s * B_ + n] * e;
      o += bf2f(oacc[((size_t)s * B_ + n) * SQ_ + d]) * e;
    }
    v = o / l;
  }
  o1b[idx] = f2bf(v);
}

// ---------------------------------------------------------------------------
extern "C" void kernel_launch(void* const* d_in, const int* in_sizes, int n_in,
                              void* d_out, int out_size, void* d_ws, size_t ws_size,
                              hipStream_t stream)
{
  const float* emb0 = (const float*)d_in[0];
  const float* ef0  = (const float*)d_in[1];
  const float* td0  = (const float*)d_in[2];
  const float* emb1 = (const float*)d_in[3];
  const float* ef1  = (const float*)d_in[4];
  const float* td1  = (const float*)d_in[5];
  const float* emb2 = (const float*)d_in[6];
  const float* Wq = (const float*)d_in[7];  const float* bq = (const float*)d_in[8];
  const float* Wk = (const float*)d_in[9];  const float* bk = (const float*)d_in[10];
  const float* Wv = (const float*)d_in[11]; const float* bv = (const float*)d_in[12];
  const float* Wo = (const float*)d_in[13]; const float* bo = (const float*)d_in[14];
  const float* W1 = (const float*)d_in[15]; const float* b1 = (const float*)d_in[16];
  const float* W2 = (const float*)d_in[17]; const float* b2 = (const float*)d_in[18];
  float* out = (float*)d_out;

  char* ws = (char*)d_ws;
  // weights bf16 @0
  u16* wb   = (u16*)ws;
  u16* wkv  = wb;
  u16* wq_b = wb + 377856;
  u16* wo_b = wb + 400896;
  u16* w1_b = wb + 423936;
  u16* w2_b = wb + 470016;
  // i=0 (all bf16 [40960][160])
  u16*   kp0b = (u16*)(ws + 1048576);
  u16*   vp0b = (u16*)(ws + 14155776);
  u16*   qp0b = (u16*)(ws + 27262976);
  u16*   nfp  = (u16*)(ws + 44302336);     // [20480][1312] bf16 row-half pack
  u16*   o0b  = (u16*)(ws + 65929216);     // [40960][160]
  u16*   a1b0 = (u16*)(ws + 1048576);      // [40960][160] (overlays kp0b)
  u16*   h0   = (u16*)(ws + 24641536);     // [40960][128]
  // i=1 (live only after i=0 fully drained)
  u16*   nf1p = (u16*)(ws + 1048576);      // [8192][1312]
  u16*   qp1b = (u16*)(ws + 22675456);     // [8192][160]
  u16*   kp1b = (u16*)(ws + 25296896);
  u16*   vp1T = (u16*)(ws + 27918336);     // [144][8192]
  u16*   o1b  = (u16*)(ws + 30277632);     // [8192][160]
  float* marr = (float*)(ws + 32899072);   // [8][8192]
  float* larr = (float*)(ws + 33161216);   // [8][8192]
  u16*   a1b1 = (u16*)(ws + 33423360);     // [8192][160]
  u16*   h1   = (u16*)(ws + 38141952);     // [8192][128]
  u16*   oacc = (u16*)(ws + 40239104);     // [8][8192][132] bf16 (~17.3 MB)

  const float scale = 0.08804509063256238f;            // 1/sqrt(129)
  const float scale2 = scale * 1.4426950408889634f;    // * log2e
  const int HROWS = 20480;

  convw_k<<<1908, 256, 0, stream>>>(Wq, Wk, Wv, Wo, W1, W2, wb);

  // ---- i = 0 -------------------------------------------------------------
  for (int h = 0; h < 2; ++h) {
    packnf_k<<<(HROWS * 328 + 255) / 256, 256, 0, stream>>>(
        emb0, ef0, td0, nfp, h * HROWS, HROWS);
    gmm_k<0, false, 1, 1, true><<<(HROWS / 64) * 2, 256, 0, stream>>>(
        41, KDP, 2, nfp, KDP, nullptr, nullptr, wkv,
        bk, kp0b + (size_t)h * HROWS * 160, 160, QD_,
        bv, vp0b + (size_t)h * HROWS * 160, 160, 1.f);
  }
  gmm_k<1, false, 1, 0, false><<<640, 256, 0, stream>>>(
      5, 160, 1, emb1, 0, nullptr, td1, wq_b,
      bq, qp0b, 160, QD_, nullptr, nullptr, 0, scale);
  attn0_k<<<B_ / 4, 256, 0, stream>>>(qp0b, kp0b, vp0b, o0b);
  // Wo -> a1b0 [.][160], zero-fill cols 129..143
  gmm_k<0, false, 1, 0, false, true><<<640, 256, 0, stream>>>(
      5, 160, 1, o0b, 160, nullptr, nullptr, wo_b,
      bo, a1b0, 160, QD_, nullptr, nullptr, 0, 1.f);
  // W1 relu -> h0: A = [a1b0 | emb1 f32], K=320
  gmm_k<2, true, 1, 0, false><<<640, 256, 0, stream>>>(
      10, 320, 1, a1b0, 160, emb1, nullptr, w1_b,
      b1, h0, 128, 128, nullptr, nullptr, 0, 1.f);
  gmm_k<0, false, 0, 0, false><<<640, 256, 0, stream>>>(
      4, 128, 1, h0, 128, nullptr, nullptr, w2_b,
      b2, out, 128, 128, nullptr, nullptr, 0, 1.f);

  // ---- i = 1 -------------------------------------------------------------
  packnf_k<<<(B_ * 328 + 255) / 256, 256, 0, stream>>>(
      emb1, ef1, td1, nf1p, 0, B_);
  hipMemsetAsync(qp1b, 0, 2621440, stream);
  hipMemsetAsync(kp1b, 0, 2621440, stream);
  hipMemsetAsync(vp1T, 0, 2359296, stream);
  gmm_k<0, false, 1, 2, true><<<(B_ / 64) * 2, 256, 0, stream>>>(
      41, KDP, 2, nf1p, KDP, nullptr, nullptr, wkv,
      bk, kp1b, QPAD, QD_, bv, vp1T, B_, 1.f);
  gmm_k<1, false, 1, 0, false><<<128, 256, 0, stream>>>(
      5, 160, 1, emb2, 0, nullptr, nullptr, wq_b,
      bq, qp1b, QPAD, QD_, nullptr, nullptr, 0, scale2);
  flashm_k<<<(B_ / QB) * NSPLIT, 512, 0, stream>>>(qp1b, kp1b, vp1T, oacc, marr, larr);
  combine_k<<<(B_ * 160 + 255) / 256, 256, 0, stream>>>(oacc, marr, larr, o1b);
  gmm_k<0, false, 1, 0, false, true><<<128, 256, 0, stream>>>(
      5, 160, 1, o1b, 160, nullptr, nullptr, wo_b,
      bo, a1b1, 160, QD_, nullptr, nullptr, 0, 1.f);
  gmm_k<2, true, 1, 0, false><<<128, 256, 0, stream>>>(
      10, 320, 1, a1b1, 160, emb2, nullptr, w1_b,
      b1, h1, 128, 128, nullptr, nullptr, 0, 1.f);
  gmm_k<0, false, 0, 0, false><<<128, 256, 0, stream>>>(
      4, 128, 1, h1, 128, nullptr, nullptr, w2_b,
      b2, out + (size_t)BK_ * D_, 128, 128, nullptr, nullptr, 0, 1.f);
}